// Round 4
// baseline (9230.108 us; speedup 1.0000x reference)
//
#include <hip/hip_runtime.h>
#include <hip/hip_bf16.h>
#include <math.h>

#define B_ 1024
#define T_ 128
#define D_ 13
#define H_ 512
#define C_ 9
#define TC_ 32              /* time chunk */
#define NC_ (T_/TC_)        /* 4 chunks */
#define NT_ (B_*T_)         /* 131072 */
#define EPS 1e-5f
#define WPAD 520            /* padded row stride (shorts): 1040B = 65*16B, 4-bank shift/row */

using frag_ab = __attribute__((ext_vector_type(8))) short;   // 8 bf16 (4 VGPRs)
using frag_cd = __attribute__((ext_vector_type(4))) float;   // 4 fp32
typedef unsigned short ushort8 __attribute__((ext_vector_type(8)));

static __device__ __forceinline__ float bf2f(unsigned short u){
  union { unsigned int i; float f; } v; v.i = ((unsigned int)u)<<16; return v.f;
}
static __device__ __forceinline__ unsigned short f2bf(float f){
  union { float f; unsigned int i; } v; v.f = f;
  unsigned int r = v.i + 0x7FFF + ((v.i >> 16) & 1);   // round-to-nearest-even
  return (unsigned short)(r >> 16);
}
static __device__ __forceinline__ float sigmoidf_(float x){ return 1.0f/(1.0f+__expf(-x)); }
static __device__ __forceinline__ float tanhf_(float x){
  return 1.0f - 2.0f/(__expf(2.0f*x)+1.0f);   // saturates via exp over/underflow
}

__global__ void k_zero(unsigned int* __restrict__ p, int n){
  int i=blockIdx.x*256+threadIdx.x; if(i<n) p[i]=0u;
}

__global__ void k_cvt_bf16(const float* __restrict__ in, unsigned short* __restrict__ out, int n){
  int i = blockIdx.x*256 + threadIdx.x;
  if(i<n) out[i] = f2bf(in[i]);
}

// ---------------- input LN + layer-1 projections (K=13, VALU), one chunk ----------------
__global__ __launch_bounds__(256) void k_proj1(
    const float* __restrict__ x, const float* __restrict__ g, const float* __restrict__ bvec,
    const float* __restrict__ WxK, const float* __restrict__ bxK,
    const float* __restrict__ Wxz, const float* __restrict__ bxz,
    unsigned short* __restrict__ xKo, unsigned short* __restrict__ zo, int t0)
{
  __shared__ float wK[H_*D_];     // 26KB
  __shared__ float wz[H_*D_];     // 26KB
  __shared__ float xn[TC_][D_];   // 1.7KB
  int tid = threadIdx.x;
  int b = blockIdx.x;             // one batch row per block, TC_ timesteps
  const float* xin = x + ((size_t)b*T_ + t0)*D_;
  for(int i=tid;i<H_*D_;i+=256){ wK[i]=WxK[i]; wz[i]=Wxz[i]; }
  for(int i=tid;i<TC_*D_;i+=256){ ((float*)xn)[i] = xin[i]; }
  __syncthreads();
  if(tid<TC_){
    float m=0.f; for(int d=0;d<D_;++d) m+=xn[tid][d]; m*=(1.0f/D_);
    float v=0.f; for(int d=0;d<D_;++d){float t=xn[tid][d]-m; v+=t*t;} v*=(1.0f/D_);
    float inv = rsqrtf(v+EPS);
    for(int d=0;d<D_;++d) xn[tid][d] = (xn[tid][d]-m)*inv*g[d]+bvec[d];
  }
  __syncthreads();
  size_t ob = (size_t)b*TC_*H_;   // chunk-local (B, TC, H)
  for(int hh=0; hh<2; ++hh){
    int h = tid + hh*256;
    float bK = bxK[h], bz = bxz[h];
    for(int r=0;r<TC_;++r){
      float aK=bK, az=bz;
      #pragma unroll
      for(int d=0;d<D_;++d){ float xv = xn[r][d]; aK += xv*wK[h*D_+d]; az += xv*wz[h*D_+d]; }
      xKo[ob + (size_t)r*H_ + h] = f2bf(aK);
      zo [ob + (size_t)r*H_ + h] = f2bf(tanhf_(az));
    }
  }
}

// ---- recurrence, LDS-resident weights: 64 groups x 4 blocks, per-step h exchange ----
// block (g,j): batch rows 16g..16g+15, out cols 128j..128j+128. Weight slice 128x512
// lives in LDS for the whole chunk. Per step: MFMA vs LDS, gate epilogue (own h state
// in fp32 regs), write bf16 slice to parity-buffered hx, release-flag, spin for the 3
// siblings, acquire, pull full h back into LDS hb. Max skew between blocks = 1 step
// (a block can't pass step t+1's spin until ALL have flagged t+1) -> 2 hx buffers.
__global__ __launch_bounds__(512,1) void k_recur_x(
    const unsigned short* __restrict__ gK, const unsigned short* __restrict__ z, // (B,TC,H)
    const unsigned short* __restrict__ Wb,   // (H,H) bf16, out x in
    const float* __restrict__ bhK,
    unsigned short* __restrict__ o,          // full (B,T,H)
    float* __restrict__ hbuf,                // (B,H) fp32 carry
    unsigned short* __restrict__ hx,         // 2 x (B,H) bf16 exchange (parity)
    unsigned int* __restrict__ flag,         // 64 x 32 (one 128B line per group)
    int t0, unsigned int fbase)
{
  __shared__ unsigned short Ws[128*WPAD];    // 133120 B
  __shared__ unsigned short hb[16][WPAD];    // 16640 B  (full 512-dim h, padded)
  int tid=threadIdx.x, lane=tid&63, w=tid>>6;
  int q=lane>>4, cl=lane&15;
  int g = blockIdx.x & 63;    // group: blocks {g, g+64, g+128, g+192} share an XCD (%8 heuristic)
  int j = blockIdx.x >> 6;    // col-slice 0..3
  int b0 = g*16, n0 = j*128;
  int nl = n0 + w*16 + cl;    // this lane's output column
  // stage weight slice (once per launch)
  for(int i=tid;i<128*64;i+=512){
    int r=i>>6, c8=i&63;
    *(ushort8*)&Ws[r*WPAD + c8*8] = *(const ushort8*)&Wb[(size_t)(n0+r)*H_ + c8*8];
  }
  // init h state
  float hp[4];
  if(t0==0){
    for(int i=tid;i<16*512;i+=512){ int r=i>>9,c=i&511; hb[r][c]=0; }
    #pragma unroll
    for(int rg=0;rg<4;++rg) hp[rg]=0.f;
  } else {
    for(int i=tid;i<16*512;i+=512){ int r=i>>9,c=i&511; hb[r][c]=f2bf(hbuf[(size_t)(b0+r)*H_+c]); }
    #pragma unroll
    for(int rg=0;rg<4;++rg) hp[rg]=hbuf[(size_t)(b0+q*4+rg)*H_+nl];
  }
  float bh = bhK[nl];
  __syncthreads();
  for(int dt=0;dt<TC_;++dt){
    unsigned short* hxc = hx + (size_t)(dt&1)*B_*H_;   // parity buffer
    // prefetch this step's gate inputs (overlaps MFMA via vmcnt queue)
    float gkv[4], zv[4];
    #pragma unroll
    for(int rg=0;rg<4;++rg){
      size_t gi = ((size_t)(b0+q*4+rg)*TC_ + dt)*H_ + nl;
      gkv[rg]=bf2f(gK[gi]); zv[rg]=bf2f(z[gi]);
    }
    // 16x16 out-tile per wave: K=512 in two independent MFMA chains
    frag_cd a0={}, a1={};
    #pragma unroll
    for(int kc=0;kc<16;kc+=2){
      frag_ab af0 = *(const frag_ab*)&hb[cl][kc*32+q*8];
      frag_ab bf0 = *(const frag_ab*)&Ws[(w*16+cl)*WPAD + kc*32+q*8];
      a0 = __builtin_amdgcn_mfma_f32_16x16x32_bf16(af0,bf0,a0,0,0,0);
      frag_ab af1 = *(const frag_ab*)&hb[cl][(kc+1)*32+q*8];
      frag_ab bf1 = *(const frag_ab*)&Ws[(w*16+cl)*WPAD + (kc+1)*32+q*8];
      a1 = __builtin_amdgcn_mfma_f32_16x16x32_bf16(af1,bf1,a1,0,0,0);
    }
    // gate epilogue: own h state stays fp32 in registers; no LDS writes here
    #pragma unroll
    for(int rg=0;rg<4;++rg){
      float gv = a0[rg]+a1[rg] + bh + gkv[rg];
      float K = sigmoidf_(gv);
      float hn = tanhf_(K*hp[rg] + (1.f-K)*zv[rg]);
      hp[rg]=hn;
      unsigned short hnb = f2bf(hn);
      hxc[(size_t)(b0+q*4+rg)*H_ + nl] = hnb;
      o[((size_t)(b0+q*4+rg)*T_ + t0+dt)*H_ + nl] = hnb;
    }
    __syncthreads();   // S2: every wave's hx stores drained (barrier implies vmcnt(0))
    if(tid==0){
      __threadfence();                         // release: wbl2 -> hx visible device-wide
      atomicAdd(&flag[g*32], 1u);
      unsigned int tgt = fbase + 4u*(dt+1);
      while(__hip_atomic_load(&flag[g*32], __ATOMIC_ACQUIRE, __HIP_MEMORY_SCOPE_AGENT) < tgt){}
      __threadfence();                         // acquire: inv L1/L2 before data reads
    }
    __syncthreads();   // S3: no wave has in-flight loads here (S2 drained them)
    // pull the full 16x512 h (all 4 slices incl. own) from hx into hb
    for(int i=tid;i<1024;i+=512){
      int s=i>>8, r=(i>>4)&15, c8=i&15;
      *(ushort8*)&hb[r][s*128 + c8*8] = *(const ushort8*)&hxc[(size_t)(b0+r)*H_ + s*128 + c8*8];
    }
    __syncthreads();   // S4: hb complete for next step's MFMA
  }
  #pragma unroll
  for(int rg=0;rg<4;++rg) hbuf[(size_t)(b0+q*4+rg)*H_+nl] = hp[rg];
}

// ---------------- BN stats (sum, sumsq per channel) ----------------
__global__ __launch_bounds__(512) void k_bnstats(const unsigned short* __restrict__ o, float* __restrict__ sums){
  int c = threadIdx.x;
  int r0 = blockIdx.x*(NT_/256);
  float s=0.f, sq=0.f;
  for(int r=0;r<NT_/256;++r){
    float v = bf2f(o[(size_t)(r0+r)*H_ + c]);
    s+=v; sq+=v*v;
  }
  atomicAdd(&sums[c], s); atomicAdd(&sums[H_+c], sq);
}

// ---------------- fold BN into projection weights / bias ----------------
__global__ void k_foldw(const float* __restrict__ WxK, const float* __restrict__ Wxz,
                        const float* __restrict__ stats, const float* __restrict__ bng,
                        unsigned short* __restrict__ Wp){
  int i = blockIdx.x*256+threadIdx.x;           // over 1024*512
  int n = i>>9, k = i&511;
  float mean = stats[k]*(1.f/NT_);
  float var  = stats[H_+k]*(1.f/NT_) - mean*mean;
  float s = bng[k]*rsqrtf(var+EPS);
  float wv = (n<H_) ? WxK[(size_t)n*H_+k] : Wxz[(size_t)(n-H_)*H_+k];
  Wp[i] = f2bf(wv*s);
}

__global__ __launch_bounds__(256) void k_foldb(const float* __restrict__ WxK, const float* __restrict__ Wxz,
                        const float* __restrict__ stats, const float* __restrict__ bng, const float* __restrict__ bnb,
                        const float* __restrict__ bxK, const float* __restrict__ bxz,
                        float* __restrict__ biasp){
  int w = threadIdx.x>>6, lane=threadIdx.x&63;
  int n = blockIdx.x*4 + w;
  const float* W = (n<H_) ? &WxK[(size_t)n*H_] : &Wxz[(size_t)(n-H_)*H_];
  float base = (n<H_) ? bxK[n] : bxz[n-H_];
  float acc=0.f;
  for(int k=lane;k<H_;k+=64){
    float mean = stats[k]*(1.f/NT_);
    float var  = stats[H_+k]*(1.f/NT_)-mean*mean;
    float s = bng[k]*rsqrtf(var+EPS);
    float t = bnb[k]-mean*s;
    acc += t*W[k];
  }
  for(int off=32;off;off>>=1) acc += __shfl_down(acc, off, 64);
  if(lane==0) biasp[n] = base + acc;
}

// ------- layers 2/3 projections, one chunk: 128x128 bf16 MFMA GEMM, N=1024=[xK|z] -------
__global__ __launch_bounds__(256) void k_proj23(
    const unsigned short* __restrict__ A,    // full o (B,T,H) bf16
    const unsigned short* __restrict__ Wp,   // (1024, 512) bf16 folded
    const float* __restrict__ biasp,         // 1024
    unsigned short* __restrict__ xKo, unsigned short* __restrict__ zo, int t0) // (B,TC,H)
{
  __shared__ __align__(16) unsigned short As[128*32];
  __shared__ __align__(16) unsigned short Bs[128*32];
  int tid=threadIdx.x, lane=tid&63, w=tid>>6;
  int q=lane>>4, cl=lane&15;
  int b0 = blockIdx.x*4;            // 4 batch rows x 32 timesteps = 128 M-rows
  int n0 = blockIdx.y*128;
  int wm = (w>>1)*64, wn=(w&1)*64;
  frag_cd acc[4][4] = {};
  int sr = tid>>1, cb = (tid&1)*16;
  size_t arow = ((size_t)(b0 + (sr>>5))*T_ + t0 + (sr&31))*H_;
  size_t brow = (size_t)(n0+sr)*H_;
  for(int k0=0;k0<H_;k0+=32){
    *(frag_ab*)&As[sr*32+cb]   = *(const frag_ab*)&A [arow + k0+cb];
    *(frag_ab*)&As[sr*32+cb+8] = *(const frag_ab*)&A [arow + k0+cb+8];
    *(frag_ab*)&Bs[sr*32+cb]   = *(const frag_ab*)&Wp[brow + k0+cb];
    *(frag_ab*)&Bs[sr*32+cb+8] = *(const frag_ab*)&Wp[brow + k0+cb+8];
    __syncthreads();
    frag_ab af[4], bfr[4];
    #pragma unroll
    for(int mt=0;mt<4;++mt) af[mt]  = *(const frag_ab*)&As[(wm+mt*16+cl)*32 + q*8];
    #pragma unroll
    for(int nt=0;nt<4;++nt) bfr[nt] = *(const frag_ab*)&Bs[(wn+nt*16+cl)*32 + q*8];
    #pragma unroll
    for(int mt=0;mt<4;++mt)
      #pragma unroll
      for(int nt=0;nt<4;++nt)
        acc[mt][nt] = __builtin_amdgcn_mfma_f32_16x16x32_bf16(af[mt], bfr[nt], acc[mt][nt],0,0,0);
    __syncthreads();
  }
  #pragma unroll
  for(int nt=0;nt<4;++nt){
    int coln = n0+wn+nt*16+cl;
    float bp = biasp[coln];
    bool isz = coln>=H_;
    #pragma unroll
    for(int mt=0;mt<4;++mt){
      #pragma unroll
      for(int rg=0;rg<4;++rg){
        int rm = wm+mt*16+q*4+rg;                       // chunk-local row = b0*32+rm
        size_t orow = (size_t)(b0*TC_ + rm)*H_;
        float v = acc[mt][nt][rg] + bp;
        if(isz) zo [orow + coln-H_] = f2bf(tanhf_(v));
        else    xKo[orow + coln]    = f2bf(v);
      }
    }
  }
}

// ---------------- head: BN3 + LN + 512->9 GEMV + log_softmax ----------------
__global__ __launch_bounds__(512) void k_head(const unsigned short* __restrict__ o,
     const float* __restrict__ stats, const float* __restrict__ bng, const float* __restrict__ bnb,
     const float* __restrict__ clng, const float* __restrict__ clnb,
     const float* __restrict__ Wc, const float* __restrict__ bc, float* __restrict__ out)
{
  __shared__ float red[8];
  __shared__ float lred[8][9];
  int tid=threadIdx.x, lane=tid&63, w=tid>>6;
  int b = blockIdx.x;
  int c = tid;
  float v = bf2f(o[((size_t)b*T_ + (T_-1))*H_ + c]);
  float mean = stats[c]*(1.f/NT_), var = stats[H_+c]*(1.f/NT_)-mean*mean;
  float s = bng[c]*rsqrtf(var+EPS);
  float y = v*s + (bnb[c]-mean*s);
  float sm=y;
  for(int off=32;off;off>>=1) sm+=__shfl_down(sm,off,64);
  if(lane==0) red[w]=sm;
  __syncthreads();
  float mu=0.f; for(int i=0;i<8;++i) mu+=red[i]; mu*=(1.f/H_);
  float d = y-mu;
  float vq = d*d;
  for(int off=32;off;off>>=1) vq+=__shfl_down(vq,off,64);
  __syncthreads();
  if(lane==0) red[w]=vq;
  __syncthreads();
  float vv=0.f; for(int i=0;i<8;++i) vv+=red[i]; vv*=(1.f/H_);
  float yn = d*rsqrtf(vv+EPS)*clng[c]+clnb[c];
  for(int cls=0;cls<C_;++cls){
    float t = yn*Wc[(size_t)cls*H_+c];
    for(int off=32;off;off>>=1) t+=__shfl_down(t,off,64);
    if(lane==0) lred[w][cls]=t;
  }
  __syncthreads();
  if(tid==0){
    float lg[C_]; float mx=-1e30f;
    for(int cls=0;cls<C_;++cls){
      float t=bc[cls]; for(int i=0;i<8;++i) t+=lred[i][cls];
      lg[cls]=t; mx=fmaxf(mx,t);
    }
    float se=0.f; for(int cls=0;cls<C_;++cls) se+=__expf(lg[cls]-mx);
    float lse=mx+logf(se);
    for(int cls=0;cls<C_;++cls) out[(size_t)b*C_+cls]=lg[cls]-lse;
  }
}

extern "C" void kernel_launch(void* const* d_in, const int* in_sizes, int n_in,
                              void* d_out, int out_size, void* d_ws, size_t ws_size,
                              hipStream_t stream)
{
  (void)in_sizes; (void)n_in; (void)out_size; (void)ws_size;
  const float* x    =(const float*)d_in[0];
  const float* inlng=(const float*)d_in[1];
  const float* inlnb=(const float*)d_in[2];
  const float* WxK1 =(const float*)d_in[3];
  const float* bxK1 =(const float*)d_in[4];
  const float* Wxz1 =(const float*)d_in[5];
  const float* bxz1 =(const float*)d_in[6];
  const float* WhK1 =(const float*)d_in[7];
  const float* bhK1 =(const float*)d_in[8];
  const float* bn1g =(const float*)d_in[9];
  const float* bn1b =(const float*)d_in[10];
  const float* WxK2 =(const float*)d_in[11];
  const float* bxK2 =(const float*)d_in[12];
  const float* Wxz2 =(const float*)d_in[13];
  const float* bxz2 =(const float*)d_in[14];
  const float* WhK2 =(const float*)d_in[15];
  const float* bhK2 =(const float*)d_in[16];
  const float* bn2g =(const float*)d_in[17];
  const float* bn2b =(const float*)d_in[18];
  const float* clng =(const float*)d_in[19];
  const float* clnb =(const float*)d_in[20];
  const float* Wc   =(const float*)d_in[21];
  const float* bc   =(const float*)d_in[22];
  float* out=(float*)d_out;

  // workspace carve: ~200 MiB total
  char* p=(char*)d_ws;
  unsigned short* o   =(unsigned short*)p; p+=(size_t)NT_*H_*2;        // 128 MiB (reused across layers)
  unsigned short* gKc =(unsigned short*)p; p+=(size_t)B_*TC_*H_*2;     // 32 MiB (one chunk)
  unsigned short* zc  =(unsigned short*)p; p+=(size_t)B_*TC_*H_*2;     // 32 MiB
  unsigned short* hx  =(unsigned short*)p; p+=(size_t)2*B_*H_*2;       // 2 MiB (parity exchange)
  float* hbuf         =(float*)p;          p+=(size_t)B_*H_*4;         // 2 MiB
  unsigned short* Wh1b=(unsigned short*)p; p+=(size_t)H_*H_*2;         // 0.5 MiB
  unsigned short* Wh2b=(unsigned short*)p; p+=(size_t)H_*H_*2;         // 0.5 MiB
  unsigned short* Wp  =(unsigned short*)p; p+=(size_t)1024*H_*2;       // 1 MiB
  float* biasp        =(float*)p;          p+=1024*4;
  float* stats        =(float*)p;          p+=3*1024*4;                // [sum|sumsq] x 3 layers
  unsigned int* flag  =(unsigned int*)p;   p+=64*32*4;                 // 64 groups x 1 cache line

  // stats (3072 words) + flags (2048 words) are contiguous: 5120 words -> 20 blocks of 256.
  // R3 BUG: launched 14 blocks (3584 threads) -> flags for groups g>=16 stayed 0xAA-poisoned
  // -> their spin passed instantly -> stale sibling h reads. 20*256=5120 covers all.
  k_zero<<<20,256,0,stream>>>((unsigned int*)stats, 3*1024 + 64*32);
  k_cvt_bf16<<<H_*H_/256,256,0,stream>>>(WhK1, Wh1b, H_*H_);
  k_cvt_bf16<<<H_*H_/256,256,0,stream>>>(WhK2, Wh2b, H_*H_);

  unsigned int ci = 0;   // global chunk index -> flag base (128 increments per chunk)

  // ---- layer 1 ----
  for(int c=0;c<NC_;++c,++ci){
    k_proj1<<<B_,256,0,stream>>>(x,inlng,inlnb,WxK1,bxK1,Wxz1,bxz1,gKc,zc,c*TC_);
    k_recur_x<<<256,512,0,stream>>>(gKc,zc,Wh1b,bhK1,o,hbuf,hx,flag,c*TC_,128u*ci);
  }
  k_bnstats<<<256,512,0,stream>>>(o, stats);

  // ---- layer 2 (BN1 folded into proj weights) ----
  k_foldw<<<1024*H_/256,256,0,stream>>>(WxK2,Wxz2,stats,bn1g,Wp);
  k_foldb<<<256,256,0,stream>>>(WxK2,Wxz2,stats,bn1g,bn1b,bxK2,bxz2,biasp);
  dim3 g23(B_/4, 8);
  for(int c=0;c<NC_;++c,++ci){
    k_proj23<<<g23,256,0,stream>>>(o,Wp,biasp,gKc,zc,c*TC_);
    k_recur_x<<<256,512,0,stream>>>(gKc,zc,Wh2b,bhK2,o,hbuf,hx,flag,c*TC_,128u*ci);
  }
  k_bnstats<<<256,512,0,stream>>>(o, stats+1024);

  // ---- layer 3 (shared weights, BN2 folded) ----
  k_foldw<<<1024*H_/256,256,0,stream>>>(WxK2,Wxz2,stats+1024,bn2g,Wp);
  k_foldb<<<256,256,0,stream>>>(WxK2,Wxz2,stats+1024,bn2g,bn2b,bxK2,bxz2,biasp);
  for(int c=0;c<NC_;++c,++ci){
    k_proj23<<<g23,256,0,stream>>>(o,Wp,biasp,gKc,zc,c*TC_);
    k_recur_x<<<256,512,0,stream>>>(gKc,zc,Wh2b,bhK2,o,hbuf,hx,flag,c*TC_,128u*ci);
  }
  k_bnstats<<<256,512,0,stream>>>(o, stats+2048);

  // ---- head ----
  k_head<<<B_,512,0,stream>>>(o, stats+2048, bn2g,bn2b, clng,clnb, Wc,bc, out);
}

// Round 5
// 5949.557 us; speedup vs baseline: 1.5514x; 1.5514x over previous
//
#include <hip/hip_runtime.h>
#include <hip/hip_bf16.h>
#include <math.h>

#define B_ 1024
#define T_ 128
#define D_ 13
#define H_ 512
#define C_ 9
#define TC_ 32              /* time chunk */
#define NC_ (T_/TC_)        /* 4 chunks */
#define NT_ (B_*T_)         /* 131072 */
#define EPS 1e-5f
#define WPAD 520            /* padded hb row stride (shorts): 1040B = 65*16B */

/* gz fragment layout: [g:64][dt:32][w:8][lane:64][sel:2][c:4][rg:4] shorts
   g stride 524288, dt stride 16384, w stride 2048, lane stride 32, sel stride 16 */
#define GZ_G 524288
#define GZ_DT 16384
#define GZ_W 2048

using frag_ab = __attribute__((ext_vector_type(8))) short;   // 8 bf16 (4 VGPRs)
using frag_cd = __attribute__((ext_vector_type(4))) float;   // 4 fp32
typedef unsigned short ushort8 __attribute__((ext_vector_type(8)));

static __device__ __forceinline__ float bf2f(unsigned short u){
  union { unsigned int i; float f; } v; v.i = ((unsigned int)u)<<16; return v.f;
}
static __device__ __forceinline__ unsigned short f2bf(float f){
  union { float f; unsigned int i; } v; v.f = f;
  unsigned int r = v.i + 0x7FFF + ((v.i >> 16) & 1);   // round-to-nearest-even
  return (unsigned short)(r >> 16);
}
static __device__ __forceinline__ float sigmoidf_(float x){ return 1.0f/(1.0f+__expf(-x)); }
static __device__ __forceinline__ float tanhf_(float x){
  return 1.0f - 2.0f/(__expf(2.0f*x)+1.0f);   // saturates via exp over/underflow
}

__global__ void k_zero(unsigned int* __restrict__ p, int n){
  int i=blockIdx.x*256+threadIdx.x; if(i<n) p[i]=0u;
}

// ---- swizzle WhK (fp32 512x512) into per-wave contiguous MFMA B-fragment stream ----
// dst = w*32768 + (kc*4+c)*512 + lane*8 + e  <-  W[row=w*64+c*16+(lane&15)][col=kc*32+(lane>>4)*8+e]
__global__ void k_swz(const float* __restrict__ Wf, unsigned short* __restrict__ Wz){
  int dst = blockIdx.x*256 + threadIdx.x;   // over 512*512
  int w = dst >> 15;
  int i = (dst >> 9) & 63;
  int L = (dst >> 3) & 63;
  int e = dst & 7;
  int kc = i >> 2, c = i & 3;
  int row = w*64 + c*16 + (L & 15);
  int col = kc*32 + ((L >> 4) << 3) + e;
  Wz[dst] = f2bf(Wf[row*H_ + col]);
}

// ---------------- input LN + layer-1 projections (K=13, VALU), one chunk ----------------
__global__ __launch_bounds__(256) void k_proj1(
    const float* __restrict__ x, const float* __restrict__ g, const float* __restrict__ bvec,
    const float* __restrict__ WxK, const float* __restrict__ bxK,
    const float* __restrict__ Wxz, const float* __restrict__ bxz,
    unsigned short* __restrict__ gz, int t0)
{
  __shared__ float wK[H_*D_];     // 26KB
  __shared__ float wz[H_*D_];     // 26KB
  __shared__ float xn[TC_][D_];   // 1.7KB
  int tid = threadIdx.x;
  int b = blockIdx.x;             // one batch row per block, TC_ timesteps
  const float* xin = x + ((size_t)b*T_ + t0)*D_;
  for(int i=tid;i<H_*D_;i+=256){ wK[i]=WxK[i]; wz[i]=Wxz[i]; }
  for(int i=tid;i<TC_*D_;i+=256){ ((float*)xn)[i] = xin[i]; }
  __syncthreads();
  if(tid<TC_){
    float m=0.f; for(int d=0;d<D_;++d) m+=xn[tid][d]; m*=(1.0f/D_);
    float v=0.f; for(int d=0;d<D_;++d){float t=xn[tid][d]-m; v+=t*t;} v*=(1.0f/D_);
    float inv = rsqrtf(v+EPS);
    for(int d=0;d<D_;++d) xn[tid][d] = (xn[tid][d]-m)*inv*g[d]+bvec[d];
  }
  __syncthreads();
  int gg = b>>4, rL = b&15, qr = rL>>2, rgr = rL&3;
  size_t gb = (size_t)gg*GZ_G;
  for(int hh=0; hh<2; ++hh){
    int h = tid + hh*256;
    int wr = h>>6, cr = (h>>4)&3, Lr = qr*16 + (h&15);
    size_t dd0 = gb + (size_t)wr*GZ_W + Lr*32 + cr*4 + rgr;
    float bK = bxK[h], bz = bxz[h];
    for(int r=0;r<TC_;++r){
      float aK=bK, az=bz;
      #pragma unroll
      for(int d=0;d<D_;++d){ float xv = xn[r][d]; aK += xv*wK[h*D_+d]; az += xv*wz[h*D_+d]; }
      size_t dd = dd0 + (size_t)r*GZ_DT;
      gz[dd]      = f2bf(aK);             // sel 0: gK
      gz[dd + 16] = f2bf(tanhf_(az));     // sel 1: z
    }
  }
}

// ---- recurrence: 64 blocks x 16 batch rows, zero inter-block comm, coalesced streams ----
// wave w owns out-cols w*64..w*64+63; B-fragments stream from pre-swizzled Wz (1KB/instr);
// gate inputs stream from fragment-ordered gz (64B/lane/step); h fp32 lives in registers.
__global__ __launch_bounds__(512,2) void k_recur2(
    const unsigned short* __restrict__ gz,   // fragment-ordered (see GZ_*)
    const unsigned short* __restrict__ Wz,   // swizzled weights, 512KB
    const float* __restrict__ bhK,
    unsigned short* __restrict__ o,          // full (B,T,H)
    float* __restrict__ hbuf, int t0)        // (B,H) fp32 carry
{
  __shared__ __align__(16) unsigned short hb[16][WPAD];   // 16.6KB bf16 h
  int tid=threadIdx.x, lane=tid&63, w=tid>>6;
  int q=lane>>4, cl=lane&15;
  int b0 = blockIdx.x*16;
  float hp[16];                  // [c*4+rg] own h fp32
  float bh[4]; int col[4];
  #pragma unroll
  for(int c=0;c<4;++c){ col[c]=w*64 + c*16 + cl; bh[c]=bhK[col[c]]; }
  if(t0==0){
    for(int i=tid;i<16*H_;i+=512){ int r=i>>9,c=i&511; hb[r][c]=0; }
    #pragma unroll
    for(int i=0;i<16;++i) hp[i]=0.f;
  } else {
    for(int i=tid;i<16*H_;i+=512){ int r=i>>9,c=i&511; hb[r][c]=f2bf(hbuf[(size_t)(b0+r)*H_+c]); }
    #pragma unroll
    for(int c=0;c<4;++c)
      #pragma unroll
      for(int rg=0;rg<4;++rg) hp[c*4+rg]=hbuf[(size_t)(b0+q*4+rg)*H_+col[c]];
  }
  const unsigned short* wb = Wz + ((size_t)w<<15);   // this wave's 64KB B-stream
  __syncthreads();
  for(int dt=0;dt<TC_;++dt){
    // gate inputs: 64B/lane, 4 coalesced 16B loads (overlap with MFMA via vmcnt queue)
    const unsigned short* gzb = gz + (size_t)(b0>>4)*GZ_G + (size_t)dt*GZ_DT + (size_t)w*GZ_W + lane*32;
    ushort8 gk0 = *(const ushort8*)gzb;
    ushort8 gk1 = *(const ushort8*)(gzb+8);
    ushort8 zz0 = *(const ushort8*)(gzb+16);
    ushort8 zz1 = *(const ushort8*)(gzb+24);
    frag_cd acc[4] = {};
    #pragma unroll
    for(int kc=0;kc<16;++kc){
      frag_ab af = *(const frag_ab*)&hb[cl][kc*32 + q*8];
      #pragma unroll
      for(int c=0;c<4;++c){
        frag_ab bf = *(const frag_ab*)&wb[(kc*4+c)*512 + lane*8];   // contiguous 1KB/wave-instr
        acc[c] = __builtin_amdgcn_mfma_f32_16x16x32_bf16(af, bf, acc[c], 0,0,0);
      }
    }
    __syncthreads();   // all waves done reading hb before epilogue rewrites it
    #pragma unroll
    for(int c=0;c<4;++c){
      #pragma unroll
      for(int rg=0;rg<4;++rg){
        int idx = c*4+rg;
        float gkv = bf2f(idx<8 ? gk0[idx] : gk1[idx-8]);
        float zv  = bf2f(idx<8 ? zz0[idx] : zz1[idx-8]);
        float gv = acc[c][rg] + bh[c] + gkv;
        float K  = sigmoidf_(gv);
        float hn = tanhf_(K*hp[idx] + (1.f-K)*zv);
        hp[idx]=hn;
        unsigned short hnb = f2bf(hn);
        hb[q*4+rg][col[c]] = hnb;
        o[((size_t)(b0+q*4+rg)*T_ + t0+dt)*H_ + col[c]] = hnb;
      }
    }
    __syncthreads();   // hb writes visible to next step's MFMA
  }
  #pragma unroll
  for(int c=0;c<4;++c)
    #pragma unroll
    for(int rg=0;rg<4;++rg) hbuf[(size_t)(b0+q*4+rg)*H_+col[c]] = hp[c*4+rg];
}

// ---------------- BN stats (sum, sumsq per channel) ----------------
__global__ __launch_bounds__(512) void k_bnstats(const unsigned short* __restrict__ o, float* __restrict__ sums){
  int c = threadIdx.x;
  int r0 = blockIdx.x*(NT_/256);
  float s=0.f, sq=0.f;
  for(int r=0;r<NT_/256;++r){
    float v = bf2f(o[(size_t)(r0+r)*H_ + c]);
    s+=v; sq+=v*v;
  }
  atomicAdd(&sums[c], s); atomicAdd(&sums[H_+c], sq);
}

// ---------------- fold BN into projection weights / bias ----------------
__global__ void k_foldw(const float* __restrict__ WxK, const float* __restrict__ Wxz,
                        const float* __restrict__ stats, const float* __restrict__ bng,
                        unsigned short* __restrict__ Wp){
  int i = blockIdx.x*256+threadIdx.x;           // over 1024*512
  int n = i>>9, k = i&511;
  float mean = stats[k]*(1.f/NT_);
  float var  = stats[H_+k]*(1.f/NT_) - mean*mean;
  float s = bng[k]*rsqrtf(var+EPS);
  float wv = (n<H_) ? WxK[(size_t)n*H_+k] : Wxz[(size_t)(n-H_)*H_+k];
  Wp[i] = f2bf(wv*s);
}

__global__ __launch_bounds__(256) void k_foldb(const float* __restrict__ WxK, const float* __restrict__ Wxz,
                        const float* __restrict__ stats, const float* __restrict__ bng, const float* __restrict__ bnb,
                        const float* __restrict__ bxK, const float* __restrict__ bxz,
                        float* __restrict__ biasp){
  int w = threadIdx.x>>6, lane=threadIdx.x&63;
  int n = blockIdx.x*4 + w;
  const float* W = (n<H_) ? &WxK[(size_t)n*H_] : &Wxz[(size_t)(n-H_)*H_];
  float base = (n<H_) ? bxK[n] : bxz[n-H_];
  float acc=0.f;
  for(int k=lane;k<H_;k+=64){
    float mean = stats[k]*(1.f/NT_);
    float var  = stats[H_+k]*(1.f/NT_)-mean*mean;
    float s = bng[k]*rsqrtf(var+EPS);
    float t = bnb[k]-mean*s;
    acc += t*W[k];
  }
  for(int off=32;off;off>>=1) acc += __shfl_down(acc, off, 64);
  if(lane==0) biasp[n] = base + acc;
}

// ------- layers 2/3 projections, one chunk: 128x128 bf16 MFMA GEMM, N=1024=[xK|z] -------
__global__ __launch_bounds__(256) void k_proj23(
    const unsigned short* __restrict__ A,    // full o (B,T,H) bf16
    const unsigned short* __restrict__ Wp,   // (1024, 512) bf16 folded
    const float* __restrict__ biasp,         // 1024
    unsigned short* __restrict__ gz, int t0) // fragment-ordered output
{
  __shared__ __align__(16) unsigned short As[128*32];
  __shared__ __align__(16) unsigned short Bs[128*32];
  int tid=threadIdx.x, lane=tid&63, w=tid>>6;
  int q=lane>>4, cl=lane&15;
  int b0p = blockIdx.x*4;           // 4 batch rows x 32 timesteps = 128 M-rows
  int n0 = blockIdx.y*128;
  int wm = (w>>1)*64, wn=(w&1)*64;
  frag_cd acc[4][4] = {};
  int sr = tid>>1, cb = (tid&1)*16;
  size_t arow = ((size_t)(b0p + (sr>>5))*T_ + t0 + (sr&31))*H_;
  size_t brow = (size_t)(n0+sr)*H_;
  for(int k0=0;k0<H_;k0+=32){
    *(frag_ab*)&As[sr*32+cb]   = *(const frag_ab*)&A [arow + k0+cb];
    *(frag_ab*)&As[sr*32+cb+8] = *(const frag_ab*)&A [arow + k0+cb+8];
    *(frag_ab*)&Bs[sr*32+cb]   = *(const frag_ab*)&Wp[brow + k0+cb];
    *(frag_ab*)&Bs[sr*32+cb+8] = *(const frag_ab*)&Wp[brow + k0+cb+8];
    __syncthreads();
    frag_ab af[4], bfr[4];
    #pragma unroll
    for(int mt=0;mt<4;++mt) af[mt]  = *(const frag_ab*)&As[(wm+mt*16+cl)*32 + q*8];
    #pragma unroll
    for(int nt=0;nt<4;++nt) bfr[nt] = *(const frag_ab*)&Bs[(wn+nt*16+cl)*32 + q*8];
    #pragma unroll
    for(int mt=0;mt<4;++mt)
      #pragma unroll
      for(int nt=0;nt<4;++nt)
        acc[mt][nt] = __builtin_amdgcn_mfma_f32_16x16x32_bf16(af[mt], bfr[nt], acc[mt][nt],0,0,0);
    __syncthreads();
  }
  #pragma unroll
  for(int nt=0;nt<4;++nt){
    int coln = n0+wn+nt*16+cl;
    float bp = biasp[coln];
    int sel = coln>=H_;
    int colh = sel ? coln-H_ : coln;
    int wr = colh>>6, cr = (colh>>4)&3;
    #pragma unroll
    for(int mt=0;mt<4;++mt){
      #pragma unroll
      for(int rg=0;rg<4;++rg){
        int rm = wm+mt*16+q*4+rg;                 // chunk-local row
        int b = b0p + (rm>>5), dt = rm&31;
        int gg = b>>4, rL = b&15;
        int Lr = (rL>>2)*16 + (colh&15), rgr = rL&3;
        size_t dd = (size_t)gg*GZ_G + (size_t)dt*GZ_DT + (size_t)wr*GZ_W + Lr*32 + sel*16 + cr*4 + rgr;
        float v = acc[mt][nt][rg] + bp;
        gz[dd] = sel ? f2bf(tanhf_(v)) : f2bf(v);
      }
    }
  }
}

// ---------------- head: BN3 + LN + 512->9 GEMV + log_softmax ----------------
__global__ __launch_bounds__(512) void k_head(const unsigned short* __restrict__ o,
     const float* __restrict__ stats, const float* __restrict__ bng, const float* __restrict__ bnb,
     const float* __restrict__ clng, const float* __restrict__ clnb,
     const float* __restrict__ Wc, const float* __restrict__ bc, float* __restrict__ out)
{
  __shared__ float red[8];
  __shared__ float lred[8][9];
  int tid=threadIdx.x, lane=tid&63, w=tid>>6;
  int b = blockIdx.x;
  int c = tid;
  float v = bf2f(o[((size_t)b*T_ + (T_-1))*H_ + c]);
  float mean = stats[c]*(1.f/NT_), var = stats[H_+c]*(1.f/NT_)-mean*mean;
  float s = bng[c]*rsqrtf(var+EPS);
  float y = v*s + (bnb[c]-mean*s);
  float sm=y;
  for(int off=32;off;off>>=1) sm+=__shfl_down(sm,off,64);
  if(lane==0) red[w]=sm;
  __syncthreads();
  float mu=0.f; for(int i=0;i<8;++i) mu+=red[i]; mu*=(1.f/H_);
  float d = y-mu;
  float vq = d*d;
  for(int off=32;off;off>>=1) vq+=__shfl_down(vq,off,64);
  __syncthreads();
  if(lane==0) red[w]=vq;
  __syncthreads();
  float vv=0.f; for(int i=0;i<8;++i) vv+=red[i]; vv*=(1.f/H_);
  float yn = d*rsqrtf(vv+EPS)*clng[c]+clnb[c];
  for(int cls=0;cls<C_;++cls){
    float t = yn*Wc[(size_t)cls*H_+c];
    for(int off=32;off;off>>=1) t+=__shfl_down(t,off,64);
    if(lane==0) lred[w][cls]=t;
  }
  __syncthreads();
  if(tid==0){
    float lg[C_]; float mx=-1e30f;
    for(int cls=0;cls<C_;++cls){
      float t=bc[cls]; for(int i=0;i<8;++i) t+=lred[i][cls];
      lg[cls]=t; mx=fmaxf(mx,t);
    }
    float se=0.f; for(int cls=0;cls<C_;++cls) se+=__expf(lg[cls]-mx);
    float lse=mx+logf(se);
    for(int cls=0;cls<C_;++cls) out[(size_t)b*C_+cls]=lg[cls]-lse;
  }
}

extern "C" void kernel_launch(void* const* d_in, const int* in_sizes, int n_in,
                              void* d_out, int out_size, void* d_ws, size_t ws_size,
                              hipStream_t stream)
{
  (void)in_sizes; (void)n_in; (void)out_size; (void)ws_size;
  const float* x    =(const float*)d_in[0];
  const float* inlng=(const float*)d_in[1];
  const float* inlnb=(const float*)d_in[2];
  const float* WxK1 =(const float*)d_in[3];
  const float* bxK1 =(const float*)d_in[4];
  const float* Wxz1 =(const float*)d_in[5];
  const float* bxz1 =(const float*)d_in[6];
  const float* WhK1 =(const float*)d_in[7];
  const float* bhK1 =(const float*)d_in[8];
  const float* bn1g =(const float*)d_in[9];
  const float* bn1b =(const float*)d_in[10];
  const float* WxK2 =(const float*)d_in[11];
  const float* bxK2 =(const float*)d_in[12];
  const float* Wxz2 =(const float*)d_in[13];
  const float* bxz2 =(const float*)d_in[14];
  const float* WhK2 =(const float*)d_in[15];
  const float* bhK2 =(const float*)d_in[16];
  const float* bn2g =(const float*)d_in[17];
  const float* bn2b =(const float*)d_in[18];
  const float* clng =(const float*)d_in[19];
  const float* clnb =(const float*)d_in[20];
  const float* Wc   =(const float*)d_in[21];
  const float* bc   =(const float*)d_in[22];
  float* out=(float*)d_out;

  // workspace carve: ~196 MiB
  char* p=(char*)d_ws;
  unsigned short* o   =(unsigned short*)p; p+=(size_t)NT_*H_*2;        // 128 MiB
  unsigned short* gz  =(unsigned short*)p; p+=(size_t)64*GZ_G*2;       // 64 MiB (one chunk, frag-ordered)
  float* hbuf         =(float*)p;          p+=(size_t)B_*H_*4;         // 2 MiB
  unsigned short* Wz1 =(unsigned short*)p; p+=(size_t)H_*H_*2;         // 0.5 MiB (swizzled)
  unsigned short* Wz2 =(unsigned short*)p; p+=(size_t)H_*H_*2;         // 0.5 MiB
  unsigned short* Wp  =(unsigned short*)p; p+=(size_t)1024*H_*2;       // 1 MiB
  float* biasp        =(float*)p;          p+=1024*4;
  float* stats        =(float*)p;          p+=3*1024*4;                // [sum|sumsq] x 3 layers

  k_zero<<<12,256,0,stream>>>((unsigned int*)stats, 3*1024);
  k_swz<<<H_*H_/256,256,0,stream>>>(WhK1, Wz1);
  k_swz<<<H_*H_/256,256,0,stream>>>(WhK2, Wz2);

  // ---- layer 1 ----
  for(int c=0;c<NC_;++c){
    k_proj1<<<B_,256,0,stream>>>(x,inlng,inlnb,WxK1,bxK1,Wxz1,bxz1,gz,c*TC_);
    k_recur2<<<64,512,0,stream>>>(gz,Wz1,bhK1,o,hbuf,c*TC_);
  }
  k_bnstats<<<256,512,0,stream>>>(o, stats);

  // ---- layer 2 (BN1 folded into proj weights) ----
  k_foldw<<<1024*H_/256,256,0,stream>>>(WxK2,Wxz2,stats,bn1g,Wp);
  k_foldb<<<256,256,0,stream>>>(WxK2,Wxz2,stats,bn1g,bn1b,bxK2,bxz2,biasp);
  dim3 g23(B_/4, 8);
  for(int c=0;c<NC_;++c){
    k_proj23<<<g23,256,0,stream>>>(o,Wp,biasp,gz,c*TC_);
    k_recur2<<<64,512,0,stream>>>(gz,Wz2,bhK2,o,hbuf,c*TC_);
  }
  k_bnstats<<<256,512,0,stream>>>(o, stats+1024);

  // ---- layer 3 (shared weights, BN2 folded) ----
  k_foldw<<<1024*H_/256,256,0,stream>>>(WxK2,Wxz2,stats+1024,bn2g,Wp);
  k_foldb<<<256,256,0,stream>>>(WxK2,Wxz2,stats+1024,bn2g,bn2b,bxK2,bxz2,biasp);
  for(int c=0;c<NC_;++c){
    k_proj23<<<g23,256,0,stream>>>(o,Wp,biasp,gz,c*TC_);
    k_recur2<<<64,512,0,stream>>>(gz,Wz2,bhK2,o,hbuf,c*TC_);
  }
  k_bnstats<<<256,512,0,stream>>>(o, stats+2048);

  // ---- head ----
  k_head<<<B_,512,0,stream>>>(o, stats+2048, bn2g,bn2b, clng,clnb, Wc,bc, out);
}

// Round 6
// 3985.806 us; speedup vs baseline: 2.3157x; 1.4927x over previous
//
#include <hip/hip_runtime.h>
#include <hip/hip_bf16.h>
#include <math.h>

#define B_ 1024
#define T_ 128
#define D_ 13
#define H_ 512
#define C_ 9
#define TC_ 32              /* time chunk */
#define NC_ (T_/TC_)        /* 4 chunks */
#define NT_ (B_*T_)         /* 131072 */
#define EPS 1e-5f
#define WPAD 520            /* padded hb row stride (shorts) */

using frag_ab = __attribute__((ext_vector_type(8))) short;   // 8 bf16 (4 VGPRs)
using frag_cd = __attribute__((ext_vector_type(4))) float;   // 4 fp32
typedef unsigned short ushort8 __attribute__((ext_vector_type(8)));

static __device__ __forceinline__ float bf2f(unsigned short u){
  union { unsigned int i; float f; } v; v.i = ((unsigned int)u)<<16; return v.f;
}
static __device__ __forceinline__ unsigned short f2bf(float f){
  union { float f; unsigned int i; } v; v.f = f;
  unsigned int r = v.i + 0x7FFF + ((v.i >> 16) & 1);   // round-to-nearest-even
  return (unsigned short)(r >> 16);
}
static __device__ __forceinline__ float sigmoidf_(float x){ return 1.0f/(1.0f+__expf(-x)); }
static __device__ __forceinline__ float tanhf_(float x){
  return 1.0f - 2.0f/(__expf(2.0f*x)+1.0f);   // saturates via exp over/underflow
}

__global__ void k_zero(unsigned int* __restrict__ p, int n){
  int i=blockIdx.x*256+threadIdx.x; if(i<n) p[i]=0u;
}

// ---- swizzle WhK (fp32 512x512) into per-wave contiguous MFMA B-fragment stream ----
// dst = w*32768 + (kc*4+c)*512 + lane*8 + e  <-  W[row=w*64+c*16+(lane&15)][col=kc*32+(lane>>4)*8+e]
// (validated round 5: recurrence consuming this layout reproduced round-2 absmax exactly)
__global__ void k_swz(const float* __restrict__ Wf, unsigned short* __restrict__ Wz){
  int dst = blockIdx.x*256 + threadIdx.x;   // over 512*512
  int w = dst >> 15;
  int i = (dst >> 9) & 63;
  int L = (dst >> 3) & 63;
  int e = dst & 7;
  int kc = i >> 2, c = i & 3;
  int row = w*64 + c*16 + (L & 15);
  int col = kc*32 + ((L >> 4) << 3) + e;
  Wz[dst] = f2bf(Wf[row*H_ + col]);
}

// ---------------- input LN + layer-1 projections (K=13, VALU), one chunk ----------------
__global__ __launch_bounds__(256) void k_proj1(
    const float* __restrict__ x, const float* __restrict__ g, const float* __restrict__ bvec,
    const float* __restrict__ WxK, const float* __restrict__ bxK,
    const float* __restrict__ Wxz, const float* __restrict__ bxz,
    unsigned short* __restrict__ xKo, unsigned short* __restrict__ zo, int t0)
{
  __shared__ float wK[H_*D_];     // 26KB
  __shared__ float wz[H_*D_];     // 26KB
  __shared__ float xn[TC_][D_];   // 1.7KB
  int tid = threadIdx.x;
  int b = blockIdx.x;             // one batch row per block, TC_ timesteps
  const float* xin = x + ((size_t)b*T_ + t0)*D_;
  for(int i=tid;i<H_*D_;i+=256){ wK[i]=WxK[i]; wz[i]=Wxz[i]; }
  for(int i=tid;i<TC_*D_;i+=256){ ((float*)xn)[i] = xin[i]; }
  __syncthreads();
  if(tid<TC_){
    float m=0.f; for(int d=0;d<D_;++d) m+=xn[tid][d]; m*=(1.0f/D_);
    float v=0.f; for(int d=0;d<D_;++d){float t=xn[tid][d]-m; v+=t*t;} v*=(1.0f/D_);
    float inv = rsqrtf(v+EPS);
    for(int d=0;d<D_;++d) xn[tid][d] = (xn[tid][d]-m)*inv*g[d]+bvec[d];
  }
  __syncthreads();
  size_t ob = (size_t)b*TC_*H_;   // chunk-local (B, TC, H)
  for(int hh=0; hh<2; ++hh){
    int h = tid + hh*256;
    float bK = bxK[h], bz = bxz[h];
    for(int r=0;r<TC_;++r){
      float aK=bK, az=bz;
      #pragma unroll
      for(int d=0;d<D_;++d){ float xv = xn[r][d]; aK += xv*wK[h*D_+d]; az += xv*wz[h*D_+d]; }
      xKo[ob + (size_t)r*H_ + h] = f2bf(aK);
      zo [ob + (size_t)r*H_ + h] = f2bf(tanhf_(az));
    }
  }
}

// ---- recurrence: 64 blocks x 16 rows; K-quarter of weights LDS-resident, rest streamed ----
// wave w owns out-cols w*64..+63. Wz wave-slice (32768 shorts): (kc*4+c)*512 + lane*8.
// kc 0..3 (first 8192 shorts/wave) live in LDS Wl; kc 4..15 stream from L2 each step.
// h fp32 in registers; bf16 copy in LDS hb. o-stores issued AFTER the hb barrier so they
// drain during the next step's MFMA phase instead of on the critical path.
__global__ __launch_bounds__(512,2) void k_recur3(
    const unsigned short* __restrict__ xK, const unsigned short* __restrict__ z, // (B,TC,H)
    const unsigned short* __restrict__ Wz,   // swizzled weights, 512KB
    const float* __restrict__ bhK,
    unsigned short* __restrict__ o,          // full (B,T,H)
    float* __restrict__ hbuf, int t0)        // (B,H) fp32 carry
{
  __shared__ __align__(16) unsigned short Wl[8*8192];     // 128KB resident quarter
  __shared__ __align__(16) unsigned short hb[16][WPAD];   // 16.6KB bf16 h
  int tid=threadIdx.x, lane=tid&63, w=tid>>6;
  int q=lane>>4, cl=lane&15;
  int b0 = blockIdx.x*16;
  // stage resident quarter: wave wv's first 8192 shorts of its 32768-short slice
  for(int i=tid;i<8192;i+=512){
    int gi = i*8;
    int wv = gi>>13, off = gi&8191;
    *(ushort8*)&Wl[gi] = *(const ushort8*)&Wz[((size_t)wv<<15) + off];
  }
  float hp[16];                  // [c*4+rg] own h fp32
  float bh[4]; int col[4];
  #pragma unroll
  for(int c=0;c<4;++c){ col[c]=w*64 + c*16 + cl; bh[c]=bhK[col[c]]; }
  if(t0==0){
    for(int i=tid;i<16*H_;i+=512){ int r=i>>9,c=i&511; hb[r][c]=0; }
    #pragma unroll
    for(int i=0;i<16;++i) hp[i]=0.f;
  } else {
    for(int i=tid;i<16*H_;i+=512){ int r=i>>9,c=i&511; hb[r][c]=f2bf(hbuf[(size_t)(b0+r)*H_+c]); }
    #pragma unroll
    for(int c=0;c<4;++c)
      #pragma unroll
      for(int rg=0;rg<4;++rg) hp[c*4+rg]=hbuf[(size_t)(b0+q*4+rg)*H_+col[c]];
  }
  const unsigned short* wb = Wz + ((size_t)w<<15);   // this wave's 64KB slice
  const unsigned short* wl = Wl + w*8192;            // its resident quarter
  __syncthreads();
  for(int dt=0;dt<TC_;++dt){
    // gate inputs (issued early; consumed after S1 -> overlap MFMA via vmcnt queue)
    float gkv[16], zv[16];
    #pragma unroll
    for(int c=0;c<4;++c)
      #pragma unroll
      for(int rg=0;rg<4;++rg){
        size_t gi = ((size_t)(b0+q*4+rg)*TC_ + dt)*H_ + col[c];
        gkv[c*4+rg]=bf2f(xK[gi]); zv[c*4+rg]=bf2f(z[gi]);
      }
    frag_cd acc[4] = {};
    #pragma unroll
    for(int kc=0;kc<16;++kc){
      frag_ab af = *(const frag_ab*)&hb[cl][kc*32 + q*8];
      #pragma unroll
      for(int c=0;c<4;++c){
        frag_ab bf = (kc<4) ? *(const frag_ab*)&wl[(kc*4+c)*512 + lane*8]
                            : *(const frag_ab*)&wb[(kc*4+c)*512 + lane*8];
        acc[c] = __builtin_amdgcn_mfma_f32_16x16x32_bf16(af, bf, acc[c], 0,0,0);
      }
    }
    __syncthreads();   // S1: all waves done reading hb
    unsigned short hnb[16];
    #pragma unroll
    for(int c=0;c<4;++c){
      #pragma unroll
      for(int rg=0;rg<4;++rg){
        int idx = c*4+rg;
        float gv = acc[c][rg] + bh[c] + gkv[idx];
        float K  = sigmoidf_(gv);
        float hn = tanhf_(K*hp[idx] + (1.f-K)*zv[idx]);
        hp[idx]=hn;
        hnb[idx]=f2bf(hn);
        hb[q*4+rg][col[c]] = hnb[idx];
      }
    }
    __syncthreads();   // S2: hb writes visible for next step's MFMA
    #pragma unroll
    for(int c=0;c<4;++c)
      #pragma unroll
      for(int rg=0;rg<4;++rg)
        o[((size_t)(b0+q*4+rg)*T_ + t0+dt)*H_ + col[c]] = hnb[c*4+rg];
  }
  #pragma unroll
  for(int c=0;c<4;++c)
    #pragma unroll
    for(int rg=0;rg<4;++rg) hbuf[(size_t)(b0+q*4+rg)*H_+col[c]] = hp[c*4+rg];
}

// ---------------- BN stats (sum, sumsq per channel) ----------------
__global__ __launch_bounds__(512) void k_bnstats(const unsigned short* __restrict__ o, float* __restrict__ sums){
  int c = threadIdx.x;
  int r0 = blockIdx.x*(NT_/256);
  float s=0.f, sq=0.f;
  for(int r=0;r<NT_/256;++r){
    float v = bf2f(o[(size_t)(r0+r)*H_ + c]);
    s+=v; sq+=v*v;
  }
  atomicAdd(&sums[c], s); atomicAdd(&sums[H_+c], sq);
}

// ---------------- fold BN into projection weights / bias ----------------
__global__ void k_foldw(const float* __restrict__ WxK, const float* __restrict__ Wxz,
                        const float* __restrict__ stats, const float* __restrict__ bng,
                        unsigned short* __restrict__ Wp){
  int i = blockIdx.x*256+threadIdx.x;           // over 1024*512
  int n = i>>9, k = i&511;
  float mean = stats[k]*(1.f/NT_);
  float var  = stats[H_+k]*(1.f/NT_) - mean*mean;
  float s = bng[k]*rsqrtf(var+EPS);
  float wv = (n<H_) ? WxK[(size_t)n*H_+k] : Wxz[(size_t)(n-H_)*H_+k];
  Wp[i] = f2bf(wv*s);
}

__global__ __launch_bounds__(256) void k_foldb(const float* __restrict__ WxK, const float* __restrict__ Wxz,
                        const float* __restrict__ stats, const float* __restrict__ bng, const float* __restrict__ bnb,
                        const float* __restrict__ bxK, const float* __restrict__ bxz,
                        float* __restrict__ biasp){
  int w = threadIdx.x>>6, lane=threadIdx.x&63;
  int n = blockIdx.x*4 + w;
  const float* W = (n<H_) ? &WxK[(size_t)n*H_] : &Wxz[(size_t)(n-H_)*H_];
  float base = (n<H_) ? bxK[n] : bxz[n-H_];
  float acc=0.f;
  for(int k=lane;k<H_;k+=64){
    float mean = stats[k]*(1.f/NT_);
    float var  = stats[H_+k]*(1.f/NT_)-mean*mean;
    float s = bng[k]*rsqrtf(var+EPS);
    float t = bnb[k]-mean*s;
    acc += t*W[k];
  }
  for(int off=32;off;off>>=1) acc += __shfl_down(acc, off, 64);
  if(lane==0) biasp[n] = base + acc;
}

// ------- layers 2/3 projections, one chunk: 128x128 bf16 MFMA GEMM, N=1024=[xK|z] -------
__global__ __launch_bounds__(256) void k_proj23(
    const unsigned short* __restrict__ A,    // full o (B,T,H) bf16
    const unsigned short* __restrict__ Wp,   // (1024, 512) bf16 folded
    const float* __restrict__ biasp,         // 1024
    unsigned short* __restrict__ xKo, unsigned short* __restrict__ zo, int t0) // (B,TC,H)
{
  __shared__ __align__(16) unsigned short As[128*32];
  __shared__ __align__(16) unsigned short Bs[128*32];
  int tid=threadIdx.x, lane=tid&63, w=tid>>6;
  int q=lane>>4, cl=lane&15;
  int b0p = blockIdx.x*4;           // 4 batch rows x 32 timesteps = 128 M-rows
  int n0 = blockIdx.y*128;
  int wm = (w>>1)*64, wn=(w&1)*64;
  frag_cd acc[4][4] = {};
  int sr = tid>>1, cb = (tid&1)*16;
  size_t arow = ((size_t)(b0p + (sr>>5))*T_ + t0 + (sr&31))*H_;
  size_t brow = (size_t)(n0+sr)*H_;
  for(int k0=0;k0<H_;k0+=32){
    *(frag_ab*)&As[sr*32+cb]   = *(const frag_ab*)&A [arow + k0+cb];
    *(frag_ab*)&As[sr*32+cb+8] = *(const frag_ab*)&A [arow + k0+cb+8];
    *(frag_ab*)&Bs[sr*32+cb]   = *(const frag_ab*)&Wp[brow + k0+cb];
    *(frag_ab*)&Bs[sr*32+cb+8] = *(const frag_ab*)&Wp[brow + k0+cb+8];
    __syncthreads();
    frag_ab af[4], bfr[4];
    #pragma unroll
    for(int mt=0;mt<4;++mt) af[mt]  = *(const frag_ab*)&As[(wm+mt*16+cl)*32 + q*8];
    #pragma unroll
    for(int nt=0;nt<4;++nt) bfr[nt] = *(const frag_ab*)&Bs[(wn+nt*16+cl)*32 + q*8];
    #pragma unroll
    for(int mt=0;mt<4;++mt)
      #pragma unroll
      for(int nt=0;nt<4;++nt)
        acc[mt][nt] = __builtin_amdgcn_mfma_f32_16x16x32_bf16(af[mt], bfr[nt], acc[mt][nt],0,0,0);
    __syncthreads();
  }
  #pragma unroll
  for(int nt=0;nt<4;++nt){
    int coln = n0+wn+nt*16+cl;
    float bp = biasp[coln];
    bool isz = coln>=H_;
    #pragma unroll
    for(int mt=0;mt<4;++mt){
      #pragma unroll
      for(int rg=0;rg<4;++rg){
        int rm = wm+mt*16+q*4+rg;                       // chunk-local row
        size_t orow = (size_t)(b0p*TC_ + rm)*H_;
        float v = acc[mt][nt][rg] + bp;
        if(isz) zo [orow + coln-H_] = f2bf(tanhf_(v));
        else    xKo[orow + coln]    = f2bf(v);
      }
    }
  }
}

// ---------------- head: BN3 + LN + 512->9 GEMV + log_softmax ----------------
__global__ __launch_bounds__(512) void k_head(const unsigned short* __restrict__ o,
     const float* __restrict__ stats, const float* __restrict__ bng, const float* __restrict__ bnb,
     const float* __restrict__ clng, const float* __restrict__ clnb,
     const float* __restrict__ Wc, const float* __restrict__ bc, float* __restrict__ out)
{
  __shared__ float red[8];
  __shared__ float lred[8][9];
  int tid=threadIdx.x, lane=tid&63, w=tid>>6;
  int b = blockIdx.x;
  int c = tid;
  float v = bf2f(o[((size_t)b*T_ + (T_-1))*H_ + c]);
  float mean = stats[c]*(1.f/NT_), var = stats[H_+c]*(1.f/NT_)-mean*mean;
  float s = bng[c]*rsqrtf(var+EPS);
  float y = v*s + (bnb[c]-mean*s);
  float sm=y;
  for(int off=32;off;off>>=1) sm+=__shfl_down(sm,off,64);
  if(lane==0) red[w]=sm;
  __syncthreads();
  float mu=0.f; for(int i=0;i<8;++i) mu+=red[i]; mu*=(1.f/H_);
  float d = y-mu;
  float vq = d*d;
  for(int off=32;off;off>>=1) vq+=__shfl_down(vq,off,64);
  __syncthreads();
  if(lane==0) red[w]=vq;
  __syncthreads();
  float vv=0.f; for(int i=0;i<8;++i) vv+=red[i]; vv*=(1.f/H_);
  float yn = d*rsqrtf(vv+EPS)*clng[c]+clnb[c];
  for(int cls=0;cls<C_;++cls){
    float t = yn*Wc[(size_t)cls*H_+c];
    for(int off=32;off;off>>=1) t+=__shfl_down(t,off,64);
    if(lane==0) lred[w][cls]=t;
  }
  __syncthreads();
  if(tid==0){
    float lg[C_]; float mx=-1e30f;
    for(int cls=0;cls<C_;++cls){
      float t=bc[cls]; for(int i=0;i<8;++i) t+=lred[i][cls];
      lg[cls]=t; mx=fmaxf(mx,t);
    }
    float se=0.f; for(int cls=0;cls<C_;++cls) se+=__expf(lg[cls]-mx);
    float lse=mx+logf(se);
    for(int cls=0;cls<C_;++cls) out[(size_t)b*C_+cls]=lg[cls]-lse;
  }
}

extern "C" void kernel_launch(void* const* d_in, const int* in_sizes, int n_in,
                              void* d_out, int out_size, void* d_ws, size_t ws_size,
                              hipStream_t stream)
{
  (void)in_sizes; (void)n_in; (void)out_size; (void)ws_size;
  const float* x    =(const float*)d_in[0];
  const float* inlng=(const float*)d_in[1];
  const float* inlnb=(const float*)d_in[2];
  const float* WxK1 =(const float*)d_in[3];
  const float* bxK1 =(const float*)d_in[4];
  const float* Wxz1 =(const float*)d_in[5];
  const float* bxz1 =(const float*)d_in[6];
  const float* WhK1 =(const float*)d_in[7];
  const float* bhK1 =(const float*)d_in[8];
  const float* bn1g =(const float*)d_in[9];
  const float* bn1b =(const float*)d_in[10];
  const float* WxK2 =(const float*)d_in[11];
  const float* bxK2 =(const float*)d_in[12];
  const float* Wxz2 =(const float*)d_in[13];
  const float* bxz2 =(const float*)d_in[14];
  const float* WhK2 =(const float*)d_in[15];
  const float* bhK2 =(const float*)d_in[16];
  const float* bn2g =(const float*)d_in[17];
  const float* bn2b =(const float*)d_in[18];
  const float* clng =(const float*)d_in[19];
  const float* clnb =(const float*)d_in[20];
  const float* Wc   =(const float*)d_in[21];
  const float* bc   =(const float*)d_in[22];
  float* out=(float*)d_out;

  // workspace carve: ~196 MiB
  char* p=(char*)d_ws;
  unsigned short* o   =(unsigned short*)p; p+=(size_t)NT_*H_*2;        // 128 MiB
  unsigned short* xK  =(unsigned short*)p; p+=(size_t)B_*TC_*H_*2;     // 32 MiB (one chunk)
  unsigned short* z   =(unsigned short*)p; p+=(size_t)B_*TC_*H_*2;     // 32 MiB
  float* hbuf         =(float*)p;          p+=(size_t)B_*H_*4;         // 2 MiB
  unsigned short* Wz1 =(unsigned short*)p; p+=(size_t)H_*H_*2;         // 0.5 MiB (swizzled)
  unsigned short* Wz2 =(unsigned short*)p; p+=(size_t)H_*H_*2;         // 0.5 MiB
  unsigned short* Wp  =(unsigned short*)p; p+=(size_t)1024*H_*2;       // 1 MiB
  float* biasp        =(float*)p;          p+=1024*4;
  float* stats        =(float*)p;          p+=3*1024*4;                // [sum|sumsq] x 3 layers

  k_zero<<<12,256,0,stream>>>((unsigned int*)stats, 3*1024);
  k_swz<<<H_*H_/256,256,0,stream>>>(WhK1, Wz1);
  k_swz<<<H_*H_/256,256,0,stream>>>(WhK2, Wz2);

  // ---- layer 1 ----
  for(int c=0;c<NC_;++c){
    k_proj1<<<B_,256,0,stream>>>(x,inlng,inlnb,WxK1,bxK1,Wxz1,bxz1,xK,z,c*TC_);
    k_recur3<<<64,512,0,stream>>>(xK,z,Wz1,bhK1,o,hbuf,c*TC_);
  }
  k_bnstats<<<256,512,0,stream>>>(o, stats);

  // ---- layer 2 (BN1 folded into proj weights) ----
  k_foldw<<<1024*H_/256,256,0,stream>>>(WxK2,Wxz2,stats,bn1g,Wp);
  k_foldb<<<256,256,0,stream>>>(WxK2,Wxz2,stats,bn1g,bn1b,bxK2,bxz2,biasp);
  dim3 g23(B_/4, 8);
  for(int c=0;c<NC_;++c){
    k_proj23<<<g23,256,0,stream>>>(o,Wp,biasp,xK,z,c*TC_);
    k_recur3<<<64,512,0,stream>>>(xK,z,Wz2,bhK2,o,hbuf,c*TC_);
  }
  k_bnstats<<<256,512,0,stream>>>(o, stats+1024);

  // ---- layer 3 (shared weights, BN2 folded) ----
  k_foldw<<<1024*H_/256,256,0,stream>>>(WxK2,Wxz2,stats+1024,bn2g,Wp);
  k_foldb<<<256,256,0,stream>>>(WxK2,Wxz2,stats+1024,bn2g,bn2b,bxK2,bxz2,biasp);
  for(int c=0;c<NC_;++c){
    k_proj23<<<g23,256,0,stream>>>(o,Wp,biasp,xK,z,c*TC_);
    k_recur3<<<64,512,0,stream>>>(xK,z,Wz2,bhK2,o,hbuf,c*TC_);
  }
  k_bnstats<<<256,512,0,stream>>>(o, stats+2048);

  // ---- head ----
  k_head<<<B_,512,0,stream>>>(o, stats+2048, bn2g,bn2b, clng,clnb, Wc,bc, out);
}

// Round 7
// 3916.693 us; speedup vs baseline: 2.3566x; 1.0176x over previous
//
#include <hip/hip_runtime.h>
#include <hip/hip_bf16.h>
#include <math.h>

#define B_ 1024
#define T_ 128
#define D_ 13
#define H_ 512
#define C_ 9
#define TC_ 32              /* time chunk */
#define NC_ (T_/TC_)        /* 4 chunks */
#define NT_ (B_*T_)         /* 131072 */
#define EPS 1e-5f
#define WPAD 520            /* padded hb row stride (shorts) */

using frag_ab = __attribute__((ext_vector_type(8))) short;   // 8 bf16 (4 VGPRs)
using frag_cd = __attribute__((ext_vector_type(4))) float;   // 4 fp32
typedef unsigned short ushort8 __attribute__((ext_vector_type(8)));

static __device__ __forceinline__ float bf2f(unsigned short u){
  union { unsigned int i; float f; } v; v.i = ((unsigned int)u)<<16; return v.f;
}
static __device__ __forceinline__ unsigned short f2bf(float f){
  union { float f; unsigned int i; } v; v.f = f;
  unsigned int r = v.i + 0x7FFF + ((v.i >> 16) & 1);   // round-to-nearest-even
  return (unsigned short)(r >> 16);
}
static __device__ __forceinline__ float sigmoidf_(float x){ return 1.0f/(1.0f+__expf(-x)); }
static __device__ __forceinline__ float tanhf_(float x){
  return 1.0f - 2.0f/(__expf(2.0f*x)+1.0f);   // saturates via exp over/underflow
}

__global__ void k_zero(unsigned int* __restrict__ p, int n){
  int i=blockIdx.x*256+threadIdx.x; if(i<n) p[i]=0u;
}

// ---- swizzle WhK (fp32 512x512) into per-wave contiguous MFMA B-fragment stream ----
// dst = w*32768 + (kc*4+c)*512 + lane*8 + e  <-  W[row=w*64+c*16+(lane&15)][col=kc*32+(lane>>4)*8+e]
__global__ void k_swz(const float* __restrict__ Wf, unsigned short* __restrict__ Wz){
  int dst = blockIdx.x*256 + threadIdx.x;   // over 512*512
  int w = dst >> 15;
  int i = (dst >> 9) & 63;
  int L = (dst >> 3) & 63;
  int e = dst & 7;
  int kc = i >> 2, c = i & 3;
  int row = w*64 + c*16 + (L & 15);
  int col = kc*32 + ((L >> 4) << 3) + e;
  Wz[dst] = f2bf(Wf[row*H_ + col]);
}

// ---------------- input LN + layer-1 projections (K=13, VALU), one chunk ----------------
__global__ __launch_bounds__(256) void k_proj1(
    const float* __restrict__ x, const float* __restrict__ g, const float* __restrict__ bvec,
    const float* __restrict__ WxK, const float* __restrict__ bxK,
    const float* __restrict__ Wxz, const float* __restrict__ bxz,
    unsigned short* __restrict__ xKo, unsigned short* __restrict__ zo, int t0)
{
  __shared__ float wK[H_*D_];     // 26KB
  __shared__ float wz[H_*D_];     // 26KB
  __shared__ float xn[TC_][D_];   // 1.7KB
  int tid = threadIdx.x;
  int b = blockIdx.x;             // one batch row per block, TC_ timesteps
  const float* xin = x + ((size_t)b*T_ + t0)*D_;
  for(int i=tid;i<H_*D_;i+=256){ wK[i]=WxK[i]; wz[i]=Wxz[i]; }
  for(int i=tid;i<TC_*D_;i+=256){ ((float*)xn)[i] = xin[i]; }
  __syncthreads();
  if(tid<TC_){
    float m=0.f; for(int d=0;d<D_;++d) m+=xn[tid][d]; m*=(1.0f/D_);
    float v=0.f; for(int d=0;d<D_;++d){float t=xn[tid][d]-m; v+=t*t;} v*=(1.0f/D_);
    float inv = rsqrtf(v+EPS);
    for(int d=0;d<D_;++d) xn[tid][d] = (xn[tid][d]-m)*inv*g[d]+bvec[d];
  }
  __syncthreads();
  size_t ob = (size_t)b*TC_*H_;   // chunk-local (B, TC, H)
  for(int hh=0; hh<2; ++hh){
    int h = tid + hh*256;
    float bK = bxK[h], bz = bxz[h];
    for(int r=0;r<TC_;++r){
      float aK=bK, az=bz;
      #pragma unroll
      for(int d=0;d<D_;++d){ float xv = xn[r][d]; aK += xv*wK[h*D_+d]; az += xv*wz[h*D_+d]; }
      xKo[ob + (size_t)r*H_ + h] = f2bf(aK);
      zo [ob + (size_t)r*H_ + h] = f2bf(tanhf_(az));
    }
  }
}

// ---- recurrence: 64 blocks x 16 rows; weights split LDS/VGPR/stream ----
// wave w owns out-cols w*64..+63; its 64KB slice = 64 frags (f=kc*4+c), 16B/lane each:
//   f 0..15  -> LDS-resident Wl (128KB/block, staged once)
//   f 16..47 -> VGPR-resident wr[32] (128 VGPRs/lane, loaded once)   <- NEW (r7)
//   f 48..63 -> streamed from L2 each step (16 loads, first use kc=12: ~48 MFMAs of cover)
// h fp32 in registers; bf16 copy in LDS hb. o-stores after S2 barrier (drain in next MFMA phase).
__global__ __launch_bounds__(512,2) void k_recur4(
    const unsigned short* __restrict__ xK, const unsigned short* __restrict__ z, // (B,TC,H)
    const unsigned short* __restrict__ Wz,   // swizzled weights, 512KB
    const float* __restrict__ bhK,
    unsigned short* __restrict__ o,          // full (B,T,H)
    float* __restrict__ hbuf, int t0)        // (B,H) fp32 carry
{
  __shared__ __align__(16) unsigned short Wl[8*8192];     // 128KB resident quarter (f0..15/wave)
  __shared__ __align__(16) unsigned short hb[16][WPAD];   // 16.6KB bf16 h
  int tid=threadIdx.x, lane=tid&63, w=tid>>6;
  int q=lane>>4, cl=lane&15;
  int b0 = blockIdx.x*16;
  const unsigned short* wb = Wz + ((size_t)w<<15);   // this wave's 64KB slice
  // stage LDS quarter: wave wv's first 8192 shorts (f0..15)
  for(int i=tid;i<8192;i+=512){
    int gi = i*8;
    int wv = gi>>13, off = gi&8191;
    *(ushort8*)&Wl[gi] = *(const ushort8*)&Wz[((size_t)wv<<15) + off];
  }
  // stage VGPR-resident f16..47 (128 VGPRs)
  frag_ab wr[32];
  #pragma unroll
  for(int f=0;f<32;++f) wr[f] = *(const frag_ab*)&wb[(16+f)*512 + lane*8];
  float hp[16];                  // [c*4+rg] own h fp32
  float bh[4]; int col[4];
  #pragma unroll
  for(int c=0;c<4;++c){ col[c]=w*64 + c*16 + cl; bh[c]=bhK[col[c]]; }
  if(t0==0){
    for(int i=tid;i<16*H_;i+=512){ int r=i>>9,c=i&511; hb[r][c]=0; }
    #pragma unroll
    for(int i=0;i<16;++i) hp[i]=0.f;
  } else {
    for(int i=tid;i<16*H_;i+=512){ int r=i>>9,c=i&511; hb[r][c]=f2bf(hbuf[(size_t)(b0+r)*H_+c]); }
    #pragma unroll
    for(int c=0;c<4;++c)
      #pragma unroll
      for(int rg=0;rg<4;++rg) hp[c*4+rg]=hbuf[(size_t)(b0+q*4+rg)*H_+col[c]];
  }
  const unsigned short* wl = Wl + w*8192;            // resident quarter
  __syncthreads();
  for(int dt=0;dt<TC_;++dt){
    // gate inputs (issued early; consumed after S1 -> overlap MFMA via vmcnt queue)
    float gkv[16], zv[16];
    #pragma unroll
    for(int c=0;c<4;++c)
      #pragma unroll
      for(int rg=0;rg<4;++rg){
        size_t gi = ((size_t)(b0+q*4+rg)*TC_ + dt)*H_ + col[c];
        gkv[c*4+rg]=bf2f(xK[gi]); zv[c*4+rg]=bf2f(z[gi]);
      }
    frag_cd acc[4] = {};
    #pragma unroll
    for(int kc=0;kc<16;++kc){
      frag_ab af = *(const frag_ab*)&hb[cl][kc*32 + q*8];
      #pragma unroll
      for(int c=0;c<4;++c){
        frag_ab bf;
        if(kc<4)       bf = *(const frag_ab*)&wl[(kc*4+c)*512 + lane*8];
        else if(kc<12) bf = wr[(kc-4)*4+c];
        else           bf = *(const frag_ab*)&wb[(kc*4+c)*512 + lane*8];
        acc[c] = __builtin_amdgcn_mfma_f32_16x16x32_bf16(af, bf, acc[c], 0,0,0);
      }
    }
    __syncthreads();   // S1: all waves done reading hb
    unsigned short hnb[16];
    #pragma unroll
    for(int c=0;c<4;++c){
      #pragma unroll
      for(int rg=0;rg<4;++rg){
        int idx = c*4+rg;
        float gv = acc[c][rg] + bh[c] + gkv[idx];
        float K  = sigmoidf_(gv);
        float hn = tanhf_(K*hp[idx] + (1.f-K)*zv[idx]);
        hp[idx]=hn;
        hnb[idx]=f2bf(hn);
        hb[q*4+rg][col[c]] = hnb[idx];
      }
    }
    __syncthreads();   // S2: hb writes visible for next step's MFMA
    #pragma unroll
    for(int c=0;c<4;++c)
      #pragma unroll
      for(int rg=0;rg<4;++rg)
        o[((size_t)(b0+q*4+rg)*T_ + t0+dt)*H_ + col[c]] = hnb[c*4+rg];
  }
  #pragma unroll
  for(int c=0;c<4;++c)
    #pragma unroll
    for(int rg=0;rg<4;++rg) hbuf[(size_t)(b0+q*4+rg)*H_+col[c]] = hp[c*4+rg];
}

// ---------------- BN stats (sum, sumsq per channel) ----------------
__global__ __launch_bounds__(512) void k_bnstats(const unsigned short* __restrict__ o, float* __restrict__ sums){
  int c = threadIdx.x;
  int r0 = blockIdx.x*(NT_/256);
  float s=0.f, sq=0.f;
  for(int r=0;r<NT_/256;++r){
    float v = bf2f(o[(size_t)(r0+r)*H_ + c]);
    s+=v; sq+=v*v;
  }
  atomicAdd(&sums[c], s); atomicAdd(&sums[H_+c], sq);
}

// ---------------- fold BN into projection weights / bias ----------------
__global__ void k_foldw(const float* __restrict__ WxK, const float* __restrict__ Wxz,
                        const float* __restrict__ stats, const float* __restrict__ bng,
                        unsigned short* __restrict__ Wp){
  int i = blockIdx.x*256+threadIdx.x;           // over 1024*512
  int n = i>>9, k = i&511;
  float mean = stats[k]*(1.f/NT_);
  float var  = stats[H_+k]*(1.f/NT_) - mean*mean;
  float s = bng[k]*rsqrtf(var+EPS);
  float wv = (n<H_) ? WxK[(size_t)n*H_+k] : Wxz[(size_t)(n-H_)*H_+k];
  Wp[i] = f2bf(wv*s);
}

__global__ __launch_bounds__(256) void k_foldb(const float* __restrict__ WxK, const float* __restrict__ Wxz,
                        const float* __restrict__ stats, const float* __restrict__ bng, const float* __restrict__ bnb,
                        const float* __restrict__ bxK, const float* __restrict__ bxz,
                        float* __restrict__ biasp){
  int w = threadIdx.x>>6, lane=threadIdx.x&63;
  int n = blockIdx.x*4 + w;
  const float* W = (n<H_) ? &WxK[(size_t)n*H_] : &Wxz[(size_t)(n-H_)*H_];
  float base = (n<H_) ? bxK[n] : bxz[n-H_];
  float acc=0.f;
  for(int k=lane;k<H_;k+=64){
    float mean = stats[k]*(1.f/NT_);
    float var  = stats[H_+k]*(1.f/NT_)-mean*mean;
    float s = bng[k]*rsqrtf(var+EPS);
    float t = bnb[k]-mean*s;
    acc += t*W[k];
  }
  for(int off=32;off;off>>=1) acc += __shfl_down(acc, off, 64);
  if(lane==0) biasp[n] = base + acc;
}

// ------- layers 2/3 projections, one chunk: 128x128 bf16 MFMA GEMM, N=1024=[xK|z] -------
__global__ __launch_bounds__(256) void k_proj23(
    const unsigned short* __restrict__ A,    // full o (B,T,H) bf16
    const unsigned short* __restrict__ Wp,   // (1024, 512) bf16 folded
    const float* __restrict__ biasp,         // 1024
    unsigned short* __restrict__ xKo, unsigned short* __restrict__ zo, int t0) // (B,TC,H)
{
  __shared__ __align__(16) unsigned short As[128*32];
  __shared__ __align__(16) unsigned short Bs[128*32];
  int tid=threadIdx.x, lane=tid&63, w=tid>>6;
  int q=lane>>4, cl=lane&15;
  int b0p = blockIdx.x*4;           // 4 batch rows x 32 timesteps = 128 M-rows
  int n0 = blockIdx.y*128;
  int wm = (w>>1)*64, wn=(w&1)*64;
  frag_cd acc[4][4] = {};
  int sr = tid>>1, cb = (tid&1)*16;
  size_t arow = ((size_t)(b0p + (sr>>5))*T_ + t0 + (sr&31))*H_;
  size_t brow = (size_t)(n0+sr)*H_;
  for(int k0=0;k0<H_;k0+=32){
    *(frag_ab*)&As[sr*32+cb]   = *(const frag_ab*)&A [arow + k0+cb];
    *(frag_ab*)&As[sr*32+cb+8] = *(const frag_ab*)&A [arow + k0+cb+8];
    *(frag_ab*)&Bs[sr*32+cb]   = *(const frag_ab*)&Wp[brow + k0+cb];
    *(frag_ab*)&Bs[sr*32+cb+8] = *(const frag_ab*)&Wp[brow + k0+cb+8];
    __syncthreads();
    frag_ab af[4], bfr[4];
    #pragma unroll
    for(int mt=0;mt<4;++mt) af[mt]  = *(const frag_ab*)&As[(wm+mt*16+cl)*32 + q*8];
    #pragma unroll
    for(int nt=0;nt<4;++nt) bfr[nt] = *(const frag_ab*)&Bs[(wn+nt*16+cl)*32 + q*8];
    #pragma unroll
    for(int mt=0;mt<4;++mt)
      #pragma unroll
      for(int nt=0;nt<4;++nt)
        acc[mt][nt] = __builtin_amdgcn_mfma_f32_16x16x32_bf16(af[mt], bfr[nt], acc[mt][nt],0,0,0);
    __syncthreads();
  }
  #pragma unroll
  for(int nt=0;nt<4;++nt){
    int coln = n0+wn+nt*16+cl;
    float bp = biasp[coln];
    bool isz = coln>=H_;
    #pragma unroll
    for(int mt=0;mt<4;++mt){
      #pragma unroll
      for(int rg=0;rg<4;++rg){
        int rm = wm+mt*16+q*4+rg;                       // chunk-local row
        size_t orow = (size_t)(b0p*TC_ + rm)*H_;
        float v = acc[mt][nt][rg] + bp;
        if(isz) zo [orow + coln-H_] = f2bf(tanhf_(v));
        else    xKo[orow + coln]    = f2bf(v);
      }
    }
  }
}

// ---------------- head: BN3 + LN + 512->9 GEMV + log_softmax ----------------
__global__ __launch_bounds__(512) void k_head(const unsigned short* __restrict__ o,
     const float* __restrict__ stats, const float* __restrict__ bng, const float* __restrict__ bnb,
     const float* __restrict__ clng, const float* __restrict__ clnb,
     const float* __restrict__ Wc, const float* __restrict__ bc, float* __restrict__ out)
{
  __shared__ float red[8];
  __shared__ float lred[8][9];
  int tid=threadIdx.x, lane=tid&63, w=tid>>6;
  int b = blockIdx.x;
  int c = tid;
  float v = bf2f(o[((size_t)b*T_ + (T_-1))*H_ + c]);
  float mean = stats[c]*(1.f/NT_), var = stats[H_+c]*(1.f/NT_)-mean*mean;
  float s = bng[c]*rsqrtf(var+EPS);
  float y = v*s + (bnb[c]-mean*s);
  float sm=y;
  for(int off=32;off;off>>=1) sm+=__shfl_down(sm,off,64);
  if(lane==0) red[w]=sm;
  __syncthreads();
  float mu=0.f; for(int i=0;i<8;++i) mu+=red[i]; mu*=(1.f/H_);
  float d = y-mu;
  float vq = d*d;
  for(int off=32;off;off>>=1) vq+=__shfl_down(vq,off,64);
  __syncthreads();
  if(lane==0) red[w]=vq;
  __syncthreads();
  float vv=0.f; for(int i=0;i<8;++i) vv+=red[i]; vv*=(1.f/H_);
  float yn = d*rsqrtf(vv+EPS)*clng[c]+clnb[c];
  for(int cls=0;cls<C_;++cls){
    float t = yn*Wc[(size_t)cls*H_+c];
    for(int off=32;off;off>>=1) t+=__shfl_down(t,off,64);
    if(lane==0) lred[w][cls]=t;
  }
  __syncthreads();
  if(tid==0){
    float lg[C_]; float mx=-1e30f;
    for(int cls=0;cls<C_;++cls){
      float t=bc[cls]; for(int i=0;i<8;++i) t+=lred[i][cls];
      lg[cls]=t; mx=fmaxf(mx,t);
    }
    float se=0.f; for(int cls=0;cls<C_;++cls) se+=__expf(lg[cls]-mx);
    float lse=mx+logf(se);
    for(int cls=0;cls<C_;++cls) out[(size_t)b*C_+cls]=lg[cls]-lse;
  }
}

extern "C" void kernel_launch(void* const* d_in, const int* in_sizes, int n_in,
                              void* d_out, int out_size, void* d_ws, size_t ws_size,
                              hipStream_t stream)
{
  (void)in_sizes; (void)n_in; (void)out_size; (void)ws_size;
  const float* x    =(const float*)d_in[0];
  const float* inlng=(const float*)d_in[1];
  const float* inlnb=(const float*)d_in[2];
  const float* WxK1 =(const float*)d_in[3];
  const float* bxK1 =(const float*)d_in[4];
  const float* Wxz1 =(const float*)d_in[5];
  const float* bxz1 =(const float*)d_in[6];
  const float* WhK1 =(const float*)d_in[7];
  const float* bhK1 =(const float*)d_in[8];
  const float* bn1g =(const float*)d_in[9];
  const float* bn1b =(const float*)d_in[10];
  const float* WxK2 =(const float*)d_in[11];
  const float* bxK2 =(const float*)d_in[12];
  const float* Wxz2 =(const float*)d_in[13];
  const float* bxz2 =(const float*)d_in[14];
  const float* WhK2 =(const float*)d_in[15];
  const float* bhK2 =(const float*)d_in[16];
  const float* bn2g =(const float*)d_in[17];
  const float* bn2b =(const float*)d_in[18];
  const float* clng =(const float*)d_in[19];
  const float* clnb =(const float*)d_in[20];
  const float* Wc   =(const float*)d_in[21];
  const float* bc   =(const float*)d_in[22];
  float* out=(float*)d_out;

  // workspace carve: ~196 MiB
  char* p=(char*)d_ws;
  unsigned short* o   =(unsigned short*)p; p+=(size_t)NT_*H_*2;        // 128 MiB
  unsigned short* xK  =(unsigned short*)p; p+=(size_t)B_*TC_*H_*2;     // 32 MiB (one chunk)
  unsigned short* z   =(unsigned short*)p; p+=(size_t)B_*TC_*H_*2;     // 32 MiB
  float* hbuf         =(float*)p;          p+=(size_t)B_*H_*4;         // 2 MiB
  unsigned short* Wz1 =(unsigned short*)p; p+=(size_t)H_*H_*2;         // 0.5 MiB (swizzled)
  unsigned short* Wz2 =(unsigned short*)p; p+=(size_t)H_*H_*2;         // 0.5 MiB
  unsigned short* Wp  =(unsigned short*)p; p+=(size_t)1024*H_*2;       // 1 MiB
  float* biasp        =(float*)p;          p+=1024*4;
  float* stats        =(float*)p;          p+=3*1024*4;                // [sum|sumsq] x 3 layers

  k_zero<<<12,256,0,stream>>>((unsigned int*)stats, 3*1024);
  k_swz<<<H_*H_/256,256,0,stream>>>(WhK1, Wz1);
  k_swz<<<H_*H_/256,256,0,stream>>>(WhK2, Wz2);

  // ---- layer 1 ----
  for(int c=0;c<NC_;++c){
    k_proj1<<<B_,256,0,stream>>>(x,inlng,inlnb,WxK1,bxK1,Wxz1,bxz1,xK,z,c*TC_);
    k_recur4<<<64,512,0,stream>>>(xK,z,Wz1,bhK1,o,hbuf,c*TC_);
  }
  k_bnstats<<<256,512,0,stream>>>(o, stats);

  // ---- layer 2 (BN1 folded into proj weights) ----
  k_foldw<<<1024*H_/256,256,0,stream>>>(WxK2,Wxz2,stats,bn1g,Wp);
  k_foldb<<<256,256,0,stream>>>(WxK2,Wxz2,stats,bn1g,bn1b,bxK2,bxz2,biasp);
  dim3 g23(B_/4, 8);
  for(int c=0;c<NC_;++c){
    k_proj23<<<g23,256,0,stream>>>(o,Wp,biasp,xK,z,c*TC_);
    k_recur4<<<64,512,0,stream>>>(xK,z,Wz2,bhK2,o,hbuf,c*TC_);
  }
  k_bnstats<<<256,512,0,stream>>>(o, stats+1024);

  // ---- layer 3 (shared weights, BN2 folded) ----
  k_foldw<<<1024*H_/256,256,0,stream>>>(WxK2,Wxz2,stats+1024,bn2g,Wp);
  k_foldb<<<256,256,0,stream>>>(WxK2,Wxz2,stats+1024,bn2g,bn2b,bxK2,bxz2,biasp);
  for(int c=0;c<NC_;++c){
    k_proj23<<<g23,256,0,stream>>>(o,Wp,biasp,xK,z,c*TC_);
    k_recur4<<<64,512,0,stream>>>(xK,z,Wz2,bhK2,o,hbuf,c*TC_);
  }
  k_bnstats<<<256,512,0,stream>>>(o, stats+2048);

  // ---- head ----
  k_head<<<B_,512,0,stream>>>(o, stats+2048, bn2g,bn2b, clng,clnb, Wc,bc, out);
}